// Round 16
// baseline (112.417 us; speedup 1.0000x reference)
//
#include <hip/hip_runtime.h>
#include <cstdint>
#include <cstddef>
#include <math.h>

// B=2, L=2048, E=1024, H=16, D=64
#define BB 2
#define LL 2048
#define EE 1024
#define HH 16
#define DD 64
#define MM (BB*LL)

typedef short short8 __attribute__((ext_vector_type(8)));
typedef float f32x4 __attribute__((ext_vector_type(4)));
typedef float f32x16 __attribute__((ext_vector_type(16)));

#define GPTR __attribute__((address_space(1)))
#define LPTR __attribute__((address_space(3)))

// pack 2 f32 -> 2 bf16 (RNE) in ONE VALU op
__device__ __forceinline__ unsigned pk_bf16(float lo, float hi) {
  unsigned r;
  asm("v_cvt_pk_bf16_f32 %0, %1, %2" : "=v"(r) : "v"(lo), "v"(hi));
  return r;
}
__device__ __forceinline__ unsigned short f32_bf16(float f) {
  return (unsigned short)pk_bf16(f, f);
}
// raw 2^x — defer-max bounds the arg; v_exp_f32(-inf)=0 in HW.
__device__ __forceinline__ float ex2(float x) {
  float r;
  asm("v_exp_f32 %0, %1" : "=v"(r) : "v"(x));
  return r;
}
// v_permlane32_swap_b32 vdst, vsrc — operands must be DISTINCT live values.
__device__ __forceinline__ void swap32(unsigned &a, unsigned &b) {
  asm("v_permlane32_swap_b32 %0, %1" : "+v"(a), "+v"(b));
}
__device__ __forceinline__ float xh_max(float v) {
  union { float f; unsigned u; } a, b;
  a.f = v;
  asm("v_mov_b32 %0, %1" : "=&v"(b.u) : "v"(a.u));
  asm("v_permlane32_swap_b32 %0, %1" : "+v"(a.u), "+v"(b.u));
  return fmaxf(a.f, b.f);
}
__device__ __forceinline__ float xh_sum(float v) {
  union { float f; unsigned u; } a, b;
  a.f = v;
  asm("v_mov_b32 %0, %1" : "=&v"(b.u) : "v"(a.u));
  asm("v_permlane32_swap_b32 %0, %1" : "+v"(a.u), "+v"(b.u));
  return a.f + b.f;
}
__device__ __forceinline__ f32x16 zero16() {
  f32x16 v;
  #pragma unroll
  for (int e = 0; e < 16; ++e) v[e] = 0.f;
  return v;
}

// ---------------- fp32 -> bf16 conversion (x + 4 weights fused) ----------------
__global__ void cvt_all(const float* __restrict__ x,  const float* __restrict__ wq,
                        const float* __restrict__ wk, const float* __restrict__ wv,
                        const float* __restrict__ wo,
                        unsigned short* __restrict__ xb,  unsigned short* __restrict__ wqb,
                        unsigned short* __restrict__ wkb, unsigned short* __restrict__ wvb,
                        unsigned short* __restrict__ wob)
{
  int i = (blockIdx.x * 256 + threadIdx.x) * 4;
  if (i >= MM * EE + 4 * EE * EE) return;
  const float* s; unsigned short* d; int off;
  if (i < MM * EE) { s = x; d = xb; off = i; }
  else {
    int k = i - MM * EE;
    int w = k >> 20;               // EE*EE = 1<<20
    off = k & (EE * EE - 1);
    s = (w == 0) ? wq : (w == 1) ? wk : (w == 2) ? wv : wo;
    d = (w == 0) ? wqb : (w == 1) ? wkb : (w == 2) ? wvb : wob;
  }
  float4 v = *(const float4*)(s + off);
  uint2 o;
  o.x = pk_bf16(v.x, v.y);
  o.y = pk_bf16(v.z, v.w);
  *(uint2*)(d + off) = o;
}

// ---------------- 128x128 bf16 GEMM (NT: A MxK, W NxK) ----------------
template<int MODE>
__global__ __launch_bounds__(256, 2)
void gemm128(const unsigned short* __restrict__ A,
             const unsigned short* __restrict__ W0,
             const unsigned short* __restrict__ W1,
             const unsigned short* __restrict__ W2,
             const float* __restrict__ mask,
             const float* __restrict__ bias,
             unsigned short* __restrict__ O0,
             unsigned short* __restrict__ O1,
             unsigned short* __restrict__ O2,
             float* __restrict__ OF)
{
  constexpr int K = EE;
  const int tid = threadIdx.x;
  const int lane = tid & 63;
  const int wid = tid >> 6;
  const int g = lane >> 4, li = lane & 15;
  const int m0 = blockIdx.y * 128;
  const int n0 = blockIdx.x * 128;
  const int z = blockIdx.z;

  const unsigned short* Wp = W0;
  if (MODE == 0) Wp = (z == 0) ? W0 : ((z == 1) ? W1 : W2);

  __shared__ unsigned short As[128 * 64];
  __shared__ unsigned short Bs[128 * 64];

  f32x4 acc[4][4];
  f32x4 zero = {0.f, 0.f, 0.f, 0.f};
  #pragma unroll
  for (int i = 0; i < 4; ++i)
    #pragma unroll
    for (int j = 0; j < 4; ++j) acc[i][j] = zero;

  const int wm = (wid >> 1) * 64;
  const int wn = (wid & 1) * 64;

  for (int kt = 0; kt < K; kt += 64) {
    #pragma unroll
    for (int j = 0; j < 4; ++j) {
      int c = j * 256 + tid;
      int row = c >> 3;
      int lcol = ((c & 7) * 16) ^ ((row & 7) << 4);
      __builtin_amdgcn_global_load_lds(
        (const GPTR void*)((const char*)(A + (size_t)(m0 + row) * K + kt) + lcol),
        (LPTR void*)((char*)As + c * 16), 16, 0, 0);
      __builtin_amdgcn_global_load_lds(
        (const GPTR void*)((const char*)(Wp + (size_t)(n0 + row) * K + kt) + lcol),
        (LPTR void*)((char*)Bs + c * 16), 16, 0, 0);
    }
    __syncthreads();

    #pragma unroll
    for (int kk = 0; kk < 2; ++kk) {
      short8 a[4], b[4];
      const int colb = (kk * 32 + g * 8) * 2;
      #pragma unroll
      for (int i = 0; i < 4; ++i) {
        int ar = wm + i * 16 + li;
        a[i] = *(const short8*)((const char*)As + ar * 128 + (colb ^ ((ar & 7) << 4)));
        int br = wn + i * 16 + li;
        b[i] = *(const short8*)((const char*)Bs + br * 128 + (colb ^ ((br & 7) << 4)));
      }
      #pragma unroll
      for (int i = 0; i < 4; ++i)
        #pragma unroll
        for (int j = 0; j < 4; ++j)
          acc[i][j] = __builtin_amdgcn_mfma_f32_16x16x32_bf16(a[i], b[j], acc[i][j], 0, 0, 0);
    }
    __syncthreads();
  }

  if (MODE == 0) {
    if (z == 2) {
      // V^T kv-blocked: per head [L/32][D=64][32], each 32-kv tile = 4KB contiguous
      #pragma unroll
      for (int i = 0; i < 4; ++i) {
        int mbase = m0 + wm + i * 16 + g * 4;
        int bb2 = mbase >> 11;
        int l0  = mbase & (LL - 1);
        float mk[4];
        #pragma unroll
        for (int r = 0; r < 4; ++r) mk[r] = mask[mbase + r];
        #pragma unroll
        for (int j = 0; j < 4; ++j) {
          int n = n0 + wn + j * 16 + li;
          int h2 = n >> 6, dd2 = n & 63;
          uint2 o;
          o.x = pk_bf16(acc[i][j][0] * mk[0], acc[i][j][1] * mk[1]);
          o.y = pk_bf16(acc[i][j][2] * mk[2], acc[i][j][3] * mk[3]);
          size_t off = (size_t)(bb2 * HH + h2) * (LL * DD)
                     + (size_t)(l0 >> 5) * (DD * 32) + dd2 * 32 + (l0 & 31);
          *(uint2*)(O2 + off) = o;
        }
      }
    } else {
      unsigned short* Op = (z == 0) ? O0 : O1;
      const float sc = (z == 0) ? 0.125f * 1.44269504088896f : 1.0f;
      #pragma unroll
      for (int i = 0; i < 4; ++i) {
        #pragma unroll
        for (int r = 0; r < 4; ++r) {
          int m = m0 + wm + i * 16 + g * 4 + r;
          float mk = mask[m] * sc;
          int bb = m >> 11;
          int l  = m & (LL - 1);
          #pragma unroll
          for (int j = 0; j < 4; ++j) {
            int n = n0 + wn + j * 16 + li;
            int h = n >> 6, d = n & 63;
            size_t off = (((size_t)(bb * HH + h)) * LL + l) * DD + d;
            Op[off] = f32_bf16(acc[i][j][r] * mk);
          }
        }
      }
    }
  } else {
    #pragma unroll
    for (int i = 0; i < 4; ++i) {
      #pragma unroll
      for (int j = 0; j < 4; ++j) {
        int n = n0 + wn + j * 16 + li;
        float bv = bias[n];
        #pragma unroll
        for (int r = 0; r < 4; ++r) {
          int m = m0 + wm + i * 16 + g * 4 + r;
          OF[(size_t)m * EE + n] = acc[i][j][r] + bv;
        }
      }
    }
  }
}

// ---------------- causal flash attention: paired independent-chain bodies ------
// Block p: q-tiles qth=63-p, qtl=p (65 processes, balanced). 2 waves kv-parity.
// Each wave splits ITS heavy tiles into E (≡w mod 4) and O (≡w+2 mod 4) states;
// every body processes TWO independent chains through ONE merged defer-branch
// (heavy-E + light, heavy-O + light in shared range; heavy-E + heavy-O beyond).
// In-register E⊕O merge at end, then the proven cross-wave LDS merge.
__global__ __launch_bounds__(128, 2)
void attn12(const unsigned short* __restrict__ Q,
            const unsigned short* __restrict__ K,
            const unsigned short* __restrict__ VT,
            unsigned short* __restrict__ Y)
{
  const int tid = threadIdx.x, lane = tid & 63, w = tid >> 6;
  const int l31 = lane & 31, hi = lane >> 5;

  const int id = blockIdx.x;
  const int lo = id & 7;                    // XCD
  const int r_ = id >> 3;
  const int bh = (r_ & 3) * 8 + lo;         // 4 heads per XCD
  const int p  = r_ >> 2;                   // pair index 0..31
  const int qth = 63 - p;                   // heavy q-tile (32..63)
  const int qtl = p;                        // light q-tile (0..31)
  const int b = bh >> 4, h = bh & (HH - 1);
  const size_t kbase = (size_t)bh * LL * DD;

  const unsigned short* Kg  = K + kbase;
  const unsigned short* VTg = VT + kbase;   // kv-blocked [L/32][64][32]

  const int qrh = qth * 32 + l31;
  const int qrl = qtl * 32 + l31;

  short8 qfh[4], qfl[4];
  {
    const unsigned short* Qr = Q + kbase + (size_t)qrh * DD + hi * 8;
    #pragma unroll
    for (int kc = 0; kc < 4; ++kc) qfh[kc] = *(const short8*)(Qr + kc * 16);
    const unsigned short* Qs = Q + kbase + (size_t)qrl * DD + hi * 8;
    #pragma unroll
    for (int kc = 0; kc < 4; ++kc) qfl[kc] = *(const short8*)(Qs + kc * 16);
  }

  // three online-softmax states: heavy-even, heavy-odd, light
  f32x16 oE0 = zero16(), oE1 = zero16();
  f32x16 oO0 = zero16(), oO1 = zero16();
  f32x16 oL0 = zero16(), oL1 = zero16();
  float mE = -INFINITY, mO = -INFINITY, mL = -INFINITY;
  float lsE0 = 0.f, lsE1 = 0.f, lsO0 = 0.f, lsO1 = 0.f, lsL0 = 0.f, lsL1 = 0.f;

  short8 kE[4], vE[4], kO[4], vO[4];

  auto loadtile = [&](short8 (&kk)[4], short8 (&vv)[4], int t2) {
    const int kv0 = t2 << 5;
    const unsigned short* Kp = Kg + ((size_t)(kv0 + l31) << 6) + hi * 8;
    #pragma unroll
    for (int kc = 0; kc < 4; ++kc) kk[kc] = *(const short8*)(Kp + kc * 16);
    const unsigned short* Vp = VTg + (size_t)(kv0 >> 5) * (DD * 32) + l31 * 32 + hi * 8;
    vv[0] = *(const short8*)(Vp);
    vv[1] = *(const short8*)(Vp + 16);
    vv[2] = *(const short8*)(Vp + 32 * 32);
    vv[3] = *(const short8*)(Vp + 32 * 32 + 16);
  };

  // 4-deep chained QK^T (min transient regs; latency hidden by chain pairing)
  auto qk4 = [&](const short8 (&ck)[4], const short8 (&qf)[4]) -> f32x16 {
    f32x16 s = __builtin_amdgcn_mfma_f32_32x32x16_bf16(ck[0], qf[0], zero16(), 0, 0, 0);
    s = __builtin_amdgcn_mfma_f32_32x32x16_bf16(ck[1], qf[1], s, 0, 0, 0);
    s = __builtin_amdgcn_mfma_f32_32x32x16_bf16(ck[2], qf[2], s, 0, 0, 0);
    s = __builtin_amdgcn_mfma_f32_32x32x16_bf16(ck[3], qf[3], s, 0, 0, 0);
    return s;
  };

  auto diagmask = [&](f32x16 &s) {
    #pragma unroll
    for (int i = 0; i < 16; ++i) {
      int kvr = (i & 3) + 8 * (i >> 2) + 4 * hi;
      if (kvr > l31) s[i] = -INFINITY;
    }
  };

  auto localmax = [&](const f32x16 &s) -> float {
    float r0 = fmaxf(fmaxf(fmaxf(s[0], s[8]),  fmaxf(s[1], s[9])),  fmaxf(s[2], s[10]));
    float r1 = fmaxf(fmaxf(fmaxf(s[3], s[11]), fmaxf(s[4], s[12])), fmaxf(s[5], s[13]));
    float r2 = fmaxf(fmaxf(s[6], s[14]), fmaxf(s[7], s[15]));
    return fmaxf(fmaxf(r0, r1), r2);
  };

  auto mkfrag = [&](const f32x16 &s, int base) -> short8 {
    unsigned a0 = pk_bf16(s[base + 0], s[base + 1]);
    unsigned a1 = pk_bf16(s[base + 2], s[base + 3]);
    unsigned b0 = pk_bf16(s[base + 4], s[base + 5]);
    unsigned b1 = pk_bf16(s[base + 6], s[base + 7]);
    swap32(a0, b0);
    swap32(a1, b1);
    union { unsigned u[4]; short8 s8; } f;
    f.u[0] = a0; f.u[1] = a1; f.u[2] = b0; f.u[3] = b1;
    return f.s8;
  };

  // exp + partial-sum + pack + PV for one already-max'd state (s has m subtracted)
  auto tail = [&](f32x16 &s, float mq, float &l0, float &l1,
                  const short8 (&cv)[4], f32x16 &o0, f32x16 &o1) {
    #pragma unroll
    for (int e = 0; e < 16; ++e) s[e] = ex2(s[e] - mq);
    l0 += (s[0] + s[8])  + (s[4] + s[12]) + (s[1] + s[9])  + (s[5] + s[13]);
    l1 += (s[2] + s[10]) + (s[6] + s[14]) + (s[3] + s[11]) + (s[7] + s[15]);
    short8 pf0 = mkfrag(s, 0), pf1 = mkfrag(s, 8);
    o0 = __builtin_amdgcn_mfma_f32_32x32x16_bf16(cv[0], pf0, o0, 0, 0, 0);
    o1 = __builtin_amdgcn_mfma_f32_32x32x16_bf16(cv[2], pf0, o1, 0, 0, 0);
    o0 = __builtin_amdgcn_mfma_f32_32x32x16_bf16(cv[1], pf1, o0, 0, 0, 0);
    o1 = __builtin_amdgcn_mfma_f32_32x32x16_bf16(cv[3], pf1, o1, 0, 0, 0);
  };

  // TWO independent chains through ONE merged defer-branch
  auto pp = [&](f32x16 &sA, float &mA, float &lA0, float &lA1,
                const short8 (&cvA)[4], f32x16 &a0, f32x16 &a1,
                f32x16 &sB, float &mB, float &lB0, float &lB1,
                const short8 (&cvB)[4], f32x16 &b0, f32x16 &b1) {
    float mvA = localmax(sA);
    float mvB = localmax(sB);
    if (!__all(fmaxf(mvA - mA, mvB - mB) <= 8.0f)) {
      float mnA = fmaxf(mA, xh_max(mvA));
      float alA = ex2(mA - mnA);               // mA=-inf -> 0 (first touch)
      mA = mnA; lA0 *= alA; lA1 *= alA;
      #pragma unroll
      for (int e = 0; e < 16; ++e) { a0[e] *= alA; a1[e] *= alA; }
      float mnB = fmaxf(mB, xh_max(mvB));
      float alB = ex2(mB - mnB);
      mB = mnB; lB0 *= alB; lB1 *= alB;
      #pragma unroll
      for (int e = 0; e < 16; ++e) { b0[e] *= alB; b1[e] *= alB; }
    }
    tail(sA, mA, lA0, lA1, cvA, a0, a1);
    tail(sB, mB, lB0, lB1, cvB, b0, b1);
  };

  // single-chain process (boundary bodies)
  auto ps = [&](f32x16 &s, float &mq, float &l0, float &l1,
                const short8 (&cv)[4], f32x16 &o0, f32x16 &o1) {
    float mv = localmax(s);
    if (!__all(mv <= mq + 8.0f)) {
      float mn = fmaxf(mq, xh_max(mv));
      float al = ex2(mq - mn);
      mq = mn; l0 *= al; l1 *= al;
      #pragma unroll
      for (int e = 0; e < 16; ++e) { o0[e] *= al; o1[e] *= al; }
    }
    tail(s, mq, l0, l1, cv, o0, o1);
  };

  // prologue: bufE <- tile w, bufO <- tile w+2 (both <= 33 <= qth always)
  loadtile(kE, vE, w);
  loadtile(kO, vO, w + 2);

  int t = w;
  while (t + 2 <= qth) {                 // full E/O pair: tiles t (E), t+2 (O)
    const bool shE = (t <= qtl), shO = (t + 2 <= qtl);
    if (shE) {
      f32x16 sE = qk4(kE, qfh);          // t < qth here (t+2<=qth), no heavy mask
      f32x16 sL = qk4(kE, qfl);
      if (t == qtl) diagmask(sL);
      pp(sE, mE, lsE0, lsE1, vE, oE0, oE1,
         sL, mL, lsL0, lsL1, vE, oL0, oL1);
      if (t + 4 <= qth) loadtile(kE, vE, t + 4);
      f32x16 sO = qk4(kO, qfh);
      if (shO) {
        f32x16 sL2 = qk4(kO, qfl);
        if (t + 2 == qtl) diagmask(sL2);
        pp(sO, mO, lsO0, lsO1, vO, oO0, oO1,
           sL2, mL, lsL0, lsL1, vO, oL0, oL1);
      } else {
        if (t + 2 == qth) diagmask(sO);
        ps(sO, mO, lsO0, lsO1, vO, oO0, oO1);
      }
      if (t + 6 <= qth) loadtile(kO, vO, t + 6);
    } else {
      f32x16 sE = qk4(kE, qfh);
      f32x16 sO = qk4(kO, qfh);
      if (t + 2 == qth) diagmask(sO);
      pp(sE, mE, lsE0, lsE1, vE, oE0, oE1,
         sO, mO, lsO0, lsO1, vO, oO0, oO1);
      if (t + 4 <= qth) loadtile(kE, vE, t + 4);
      if (t + 6 <= qth) loadtile(kO, vO, t + 6);
    }
    t += 4;
  }
  if (t <= qth) {                        // trailing single tile (in bufE)
    f32x16 sE = qk4(kE, qfh);
    if (t == qth) diagmask(sE);
    if (t <= qtl) {
      f32x16 sL = qk4(kE, qfl);
      if (t == qtl) diagmask(sL);
      pp(sE, mE, lsE0, lsE1, vE, oE0, oE1,
         sL, mL, lsL0, lsL1, vE, oL0, oL1);
    } else {
      ps(sE, mE, lsE0, lsE1, vE, oE0, oE1);
    }
  }

  // ---- intra-wave heavy merge: E ⊕ O (same-lane register ops, no barrier) ----
  float mH = fmaxf(mE, mO);
  float aE = ex2(fmaxf(mE - mH, -200.0f));
  float aO = ex2(fmaxf(mO - mH, -200.0f));
  float lsH = (lsE0 + lsE1) * aE + (lsO0 + lsO1) * aO;
  f32x16 oh0, oh1;
  #pragma unroll
  for (int e = 0; e < 16; ++e) {
    oh0[e] = oE0[e] * aE + oO0[e] * aO;
    oh1[e] = oE1[e] * aE + oO1[e] * aO;
  }
  float lsL = lsL0 + lsL1;

  // ---- cross-wave merge via LDS (single barrier), both q-tiles ----
  __shared__ float mg[2][64][34];
  if (w == 1) {
    mg[0][lane][0] = mH; mg[0][lane][1] = lsH;
    mg[1][lane][0] = mL; mg[1][lane][1] = lsL;
    #pragma unroll
    for (int e = 0; e < 16; ++e) {
      mg[0][lane][2 + e] = oh0[e]; mg[0][lane][18 + e] = oh1[e];
      mg[1][lane][2 + e] = oL0[e]; mg[1][lane][18 + e] = oL1[e];
    }
  }
  __syncthreads();
  if (w == 0) {
    #pragma unroll
    for (int q = 0; q < 2; ++q) {
      float mw = (q == 0) ? mH : mL;
      float lw = (q == 0) ? lsH : lsL;
      const f32x16& o0 = (q == 0) ? oh0 : oL0;
      const f32x16& o1 = (q == 0) ? oh1 : oL1;
      int qrow = (q == 0) ? qrh : qrl;
      float m1 = mg[q][lane][0], l1 = mg[q][lane][1];
      float M = fmaxf(mw, m1);
      float a0 = ex2(fmaxf(mw - M, -200.0f));   // -inf-(-inf) NaN guard
      float a1 = ex2(fmaxf(m1 - M, -200.0f));
      float LtH = lw * a0 + l1 * a1;            // half-row total
      float Lt = xh_sum(LtH);                   // row total (single permlane)
      float inv = 1.0f / Lt;
      unsigned short* Yr = Y + ((size_t)b * LL + qrow) * EE + h * DD;
      #pragma unroll
      for (int rg = 0; rg < 4; ++rg) {
        uint2 u0, u1;
        int i = rg * 4;
        u0.x = pk_bf16((o0[i]     * a0 + mg[q][lane][2 + i]  * a1) * inv,
                       (o0[i + 1] * a0 + mg[q][lane][3 + i]  * a1) * inv);
        u0.y = pk_bf16((o0[i + 2] * a0 + mg[q][lane][4 + i]  * a1) * inv,
                       (o0[i + 3] * a0 + mg[q][lane][5 + i]  * a1) * inv);
        u1.x = pk_bf16((o1[i]     * a0 + mg[q][lane][18 + i] * a1) * inv,
                       (o1[i + 1] * a0 + mg[q][lane][19 + i] * a1) * inv);
        u1.y = pk_bf16((o1[i + 2] * a0 + mg[q][lane][20 + i] * a1) * inv,
                       (o1[i + 3] * a0 + mg[q][lane][21 + i] * a1) * inv);
        *(uint2*)(Yr + rg * 8 + hi * 4) = u0;
        *(uint2*)(Yr + 32 + rg * 8 + hi * 4) = u1;
      }
    }
  }
}

// ---------------- launch ----------------
extern "C" void kernel_launch(void* const* d_in, const int* in_sizes, int n_in,
                              void* d_out, int out_size, void* d_ws, size_t ws_size,
                              hipStream_t stream) {
  const float* x    = (const float*)d_in[0];
  const float* mask = (const float*)d_in[1];
  const float* Wq   = (const float*)d_in[2];
  const float* Wk   = (const float*)d_in[3];
  const float* Wv   = (const float*)d_in[4];
  const float* Wo   = (const float*)d_in[5];
  const float* bo   = (const float*)d_in[6];
  float* out = (float*)d_out;

  char* ws = (char*)d_ws;
  unsigned short* xb  = (unsigned short*)(ws);
  unsigned short* wqb = (unsigned short*)(ws + ((size_t)8  << 20));
  unsigned short* wkb = (unsigned short*)(ws + ((size_t)10 << 20));
  unsigned short* wvb = (unsigned short*)(ws + ((size_t)12 << 20));
  unsigned short* wob = (unsigned short*)(ws + ((size_t)14 << 20));
  unsigned short* Qb  = (unsigned short*)(ws + ((size_t)16 << 20));
  unsigned short* Kb  = (unsigned short*)(ws + ((size_t)24 << 20));
  unsigned short* VTb = (unsigned short*)(ws + ((size_t)32 << 20));
  unsigned short* Yb  = (unsigned short*)(ws + ((size_t)40 << 20));

  cvt_all<<<8192, 256, 0, stream>>>(x, Wq, Wk, Wv, Wo, xb, wqb, wkb, wvb, wob);

  gemm128<0><<<dim3(EE / 128, MM / 128, 3), 256, 0, stream>>>(
      xb, wqb, wkb, wvb, mask, nullptr, Qb, Kb, VTb, nullptr);

  attn12<<<dim3(1024), 128, 0, stream>>>(Qb, Kb, VTb, Yb);

  gemm128<1><<<dim3(EE / 128, MM / 128, 1), 256, 0, stream>>>(
      Yb, wob, nullptr, nullptr, nullptr, bo, nullptr, nullptr, nullptr, out);
}